// Round 12
// baseline (252.469 us; speedup 1.0000x reference)
//
#include <hip/hip_runtime.h>

// SAGEConv: out = h@W_self.T + b_self + b_nb + segsum(val * (h@W_nb.T)[col])
// R21 = R19 base (240.4us best; R20's wide gather was a null result) with
//     gemm restructured for occupancy: each wave now covers 32 output cols
//     (wf 64->32 regs, acc 64->32) and the 256 dual-cols come from PAIRED
//     blocks: bid in [0,512) -> out cols (rows' self part), bid+512 ->
//     tmpb cols, walking IDENTICAL tiles on the SAME XCD (512%8==0) so the
//     duplicated h staging is L2-hot. __launch_bounds__(256,4) forces
//     VGPR<=128 -> 16 waves/CU vs measured 4.3 (13.5% occ) before. gemm
//     was 1.9 TB/s duty-limited; this raises load concurrency 3.7x.
//     wc_scatter / sort_aggregate: exact R19 (proven).

constexpr int NN = 100000;
constexpr int NE = 1600000;
constexpr int D  = 128;
constexpr int NBUCK  = 500;                // buckets of BROWS rows
constexpr int BROWS  = 200;                // 500*200 = 100000 exactly
constexpr int BCAP   = 3584;               // mean 3200 + ~6.8 sigma
constexpr int CHUNK  = 4096;               // edges per wc chunk
constexpr int NCH    = (NE + CHUNK - 1) / CHUNK;   // 391
constexpr int GM     = 64;                 // gemm M-tile rows
constexpr int NT     = (NN + GM - 1) / GM; // 1563 tiles total
constexpr int GW     = 512;                // tile walkers (x2 col-halves = 1024 blocks)
constexpr int LP     = 132;                // LDS bf16 pitch (2-way = free)

typedef __bf16 bf16x8 __attribute__((ext_vector_type(8)));
typedef float  f32x4  __attribute__((ext_vector_type(4)));
typedef float  f32x2  __attribute__((ext_vector_type(2)));
typedef unsigned short u16x4 __attribute__((ext_vector_type(4)));

// ---------------- Dual GEMM (persistent, pipelined, slim-register) -------
// Block pair (b, b+512): same tile walk, colD = 0 (out+bias) / 128 (tmpb).
__global__ __launch_bounds__(256, 4) void gemm_mfma(
    const float* __restrict__ h,
    const float* __restrict__ Wself,
    const float* __restrict__ Wnb,
    const float* __restrict__ bself,
    const float* __restrict__ bnb,
    float* __restrict__ out,
    __bf16* __restrict__ tmpb,
    int* __restrict__ gcount)
{
    __shared__ __bf16 hs[2][GM * LP];   // 2 x 16.9 KB
    const int t    = threadIdx.x;
    const int w    = t >> 6;
    const int lane = t & 63;
    const int l15  = lane & 15;
    const int quad = lane >> 4;
    const int bid  = blockIdx.x;
    const int colD = (bid >= GW) ? 128 : 0;   // dual-col half this block owns
    const int walk = bid & (GW - 1);          // tile walker id

    // Zero gcount (500 ints): blocks 0-1 cover it.
    {
        int i = bid * 256 + t;
        if (i < NBUCK) gcount[i] = 0;
    }

    // W frags (A operand): dual-row wrow = colD + w*32 + ns*16 + l15,
    // k = quad*8 + kk*32 + j. wf[2][4] = 32 VGPR (was 64).
    bf16x8 wf[2][4];
    #pragma unroll
    for (int ns = 0; ns < 2; ++ns) {
        int wrow = colD + w * 32 + ns * 16 + l15;
        const float* wr = (wrow < D) ? (Wself + (size_t)wrow * D)
                                     : (Wnb + (size_t)(wrow - D) * D);
        #pragma unroll
        for (int kk = 0; kk < 4; ++kk) {
            f32x4 lo = *(const f32x4*)(wr + kk * 32 + quad * 8);
            f32x4 hi = *(const f32x4*)(wr + kk * 32 + quad * 8 + 4);
            bf16x8 bb;
            #pragma unroll
            for (int j = 0; j < 4; ++j) { bb[j] = (__bf16)lo[j]; bb[4 + j] = (__bf16)hi[j]; }
            wf[ns][kk] = bb;
        }
    }
    // Bias vectors (only the colD==0 half stores to out).
    f32x4 biasv[2];
    #pragma unroll
    for (int ns = 0; ns < 2; ++ns) {
        int col = w * 32 + ns * 16 + quad * 4;
        if (colD == 0) {
            f32x4 b1 = *(const f32x4*)(bself + col);
            f32x4 b2 = *(const f32x4*)(bnb + col);
            biasv[ns] = b1 + b2;
        } else biasv[ns] = (f32x4){0.f, 0.f, 0.f, 0.f};
    }

    // Per-thread staging geometry (constant across tiles).
    int srow[4], scol[4];
    #pragma unroll
    for (int it = 0; it < 4; ++it) {
        int idx = it * 2048 + t * 8;
        srow[it] = idx >> 7;
        scol[it] = idx & 127;
    }

    // Prologue: stage first tile into hs[0].
    {
        const int row0 = walk * GM;
        #pragma unroll
        for (int it = 0; it < 4; ++it) {
            int gr = row0 + srow[it]; if (gr >= NN) gr = NN - 1;
            f32x4 lo = *(const f32x4*)(h + (size_t)gr * D + scol[it]);
            f32x4 hi = *(const f32x4*)(h + (size_t)gr * D + scol[it] + 4);
            bf16x8 v;
            #pragma unroll
            for (int j = 0; j < 4; ++j) { v[j] = (__bf16)lo[j]; v[4 + j] = (__bf16)hi[j]; }
            *(bf16x8*)(&hs[0][srow[it] * LP + scol[it]]) = v;
        }
    }
    __syncthreads();

    int buf = 0;
    for (int tile = walk; tile < NT; tile += GW) {
        const int row0 = tile * GM;
        const bool hasn = (tile + GW) < NT;

        // Issue next tile's global loads NOW (in flight across MFMA).
        f32x4 pf[8];
        if (hasn) {
            const int nrow0 = (tile + GW) * GM;
            #pragma unroll
            for (int it = 0; it < 4; ++it) {
                int gr = nrow0 + srow[it]; if (gr >= NN) gr = NN - 1;
                pf[it * 2]     = *(const f32x4*)(h + (size_t)gr * D + scol[it]);
                pf[it * 2 + 1] = *(const f32x4*)(h + (size_t)gr * D + scol[it] + 4);
            }
        }

        // Compute: acc[mi][ns] (32 accum regs; was 64).
        // C-layout (swapped operands): C col(lane&15)=out-row=mi*16+l15;
        // C row(quad*4+reg)=out-col.
        f32x4 acc[4][2];
        #pragma unroll
        for (int mi = 0; mi < 4; ++mi)
            #pragma unroll
            for (int ns = 0; ns < 2; ++ns) acc[mi][ns] = (f32x4){0.f, 0.f, 0.f, 0.f};

        const __bf16* hb = hs[buf];
        #pragma unroll
        for (int mi = 0; mi < 4; ++mi) {
            bf16x8 hf[4];
            #pragma unroll
            for (int kk = 0; kk < 4; ++kk)
                hf[kk] = *(const bf16x8*)(&hb[(mi * 16 + l15) * LP + quad * 8 + kk * 32]);
            #pragma unroll
            for (int ns = 0; ns < 2; ++ns)
                #pragma unroll
                for (int kk = 0; kk < 4; ++kk)
                    acc[mi][ns] = __builtin_amdgcn_mfma_f32_16x16x32_bf16(wf[ns][kk], hf[kk], acc[mi][ns], 0, 0, 0);
        }

        // Convert + write the prefetched tile into the other LDS buffer.
        if (hasn) {
            #pragma unroll
            for (int it = 0; it < 4; ++it) {
                bf16x8 v;
                #pragma unroll
                for (int j = 0; j < 4; ++j) {
                    v[j]     = (__bf16)pf[it * 2][j];
                    v[4 + j] = (__bf16)pf[it * 2 + 1][j];
                }
                *(bf16x8*)(&hs[buf ^ 1][srow[it] * LP + scol[it]]) = v;
            }
        }
        __syncthreads();

        // Epilogue: this block's col-half only.
        #pragma unroll
        for (int mi = 0; mi < 4; ++mi) {
            int row = row0 + mi * 16 + l15;
            if (row < NN) {
                if (colD == 0) {
                    #pragma unroll
                    for (int ns = 0; ns < 2; ++ns) {
                        int col = w * 32 + ns * 16 + quad * 4;
                        *(f32x4*)(out + (size_t)row * D + col) = acc[mi][ns] + biasv[ns];
                    }
                } else {
                    #pragma unroll
                    for (int ns = 0; ns < 2; ++ns) {
                        int col = w * 32 + ns * 16 + quad * 4;
                        u16x4 v;
                        #pragma unroll
                        for (int i = 0; i < 4; ++i) {
                            __bf16 b = (__bf16)acc[mi][ns][i];
                            v[i] = *(unsigned short*)&b;
                        }
                        *(u16x4*)(tmpb + (size_t)row * D + col) = v;
                    }
                }
            }
        }
        buf ^= 1;
    }
}

// ------- Write-combined bucket scatter (500 bins, CHUNK 4096, 512 thr) ---
__global__ __launch_bounds__(512) void wc_scatter(
    const int* __restrict__ erow, const int* __restrict__ ecol,
    const float* __restrict__ eval_,
    int* __restrict__ gcount, int2* __restrict__ epair)
{
    __shared__ int  cnt[NBUCK];
    __shared__ int  lscan[NBUCK];
    __shared__ int  gbase[NBUCK];
    __shared__ int  ss[512];
    __shared__ int2 sbuf[CHUNK];
    __shared__ int  saddr[CHUNK];
    __shared__ int  s_total;

    const int t  = threadIdx.x;
    const int c0 = blockIdx.x * CHUNK;

    for (int b = t; b < NBUCK; b += 512) cnt[b] = 0;
    __syncthreads();

    int   bp[8];       // b | rlo<<9 | pos<<17  (or -1 if OOB)
    int   colr[8];
    float valr[8];
    #pragma unroll
    for (int j = 0; j < 8; ++j) {
        int e = c0 + j * 512 + t;
        if (e < NE) {
            int r   = erow[e];
            colr[j] = ecol[e];
            valr[j] = eval_[e];
            int b   = r / BROWS;
            int rlo = r - b * BROWS;
            int pos = atomicAdd(&cnt[b], 1);
            bp[j]   = b | (rlo << 9) | (pos << 17);
        } else bp[j] = -1;
    }
    __syncthreads();

    // Scan 512 slots, 1/thread Hillis-Steele.
    ss[t] = (t < NBUCK) ? cnt[t] : 0;
    __syncthreads();
    for (int off = 1; off < 512; off <<= 1) {
        int v = ss[t] + ((t >= off) ? ss[t - off] : 0);
        __syncthreads();
        ss[t] = v;
        __syncthreads();
    }
    if (t < NBUCK) {
        int n = cnt[t];
        lscan[t] = ss[t] - n;
        gbase[t] = (n > 0) ? atomicAdd(&gcount[t], n) : 0;
    }
    if (t == 0) s_total = ss[511];
    __syncthreads();

    #pragma unroll
    for (int j = 0; j < 8; ++j) {
        if (bp[j] >= 0) {
            int b   = bp[j] & 511;
            int rlo = (bp[j] >> 9) & 255;
            int pos = bp[j] >> 17;
            int slot = lscan[b] + pos;
            sbuf[slot]  = make_int2(colr[j] | (rlo << 17), __float_as_int(valr[j]));
            saddr[slot] = b * BCAP + gbase[b] + pos;
        }
    }
    __syncthreads();

    int ce = s_total;
    for (int i = t; i < ce; i += 512)
        epair[saddr[i]] = sbuf[i];
}

// ---------------- Fused bucket sort + aggregate (exact R19, 85.6us) ------
__global__ __launch_bounds__(512, 4) void sort_aggregate(
    const int2* __restrict__ epair, const int* __restrict__ gcount,
    const __bf16* __restrict__ tmpb, float* __restrict__ out)
{
    __shared__ int  cnt[BROWS];
    __shared__ int  off2[BROWS];
    __shared__ int  cur[BROWS];
    __shared__ int  ss[256];
    __shared__ int2 sorted[BCAP];

    const int t = threadIdx.x;
    const int b = blockIdx.x;
    int n = gcount[b];
    if (n > BCAP) n = BCAP;
    const int2* src = epair + (size_t)b * BCAP;

    if (t < BROWS) cnt[t] = 0;
    __syncthreads();

    int2 r[8];
    int  nr = 0;
    for (int i = t; i < n; i += 512) {
        int2 p = src[i];
        r[nr++] = p;
        atomicAdd(&cnt[(p.x >> 17) & 255], 1);
    }
    __syncthreads();

    if (t < 256) ss[t] = (t < BROWS) ? cnt[t] : 0;
    __syncthreads();
    for (int o = 1; o < 256; o <<= 1) {
        int y = 0;
        if (t < 256 && t >= o) y = ss[t - o];
        __syncthreads();
        if (t < 256) ss[t] += y;
        __syncthreads();
    }
    if (t < BROWS) {
        int v = cnt[t];
        off2[t] = ss[t] - v;
        cur[t]  = ss[t] - v;
    }
    __syncthreads();

    for (int j = 0; j < nr; ++j) {
        int slot = atomicAdd(&cur[(r[j].x >> 17) & 255], 1);
        sorted[slot] = r[j];
    }
    __syncthreads();
    // Now: row rl's edges are sorted[off2[rl] .. cur[rl]).

    // ---- Aggregate phase: 8 waves x 25 rows, gather tmpb, RMW out. ----
    const int wv   = t >> 6;
    const int lane = t & 63;
    const __bf16* tb = tmpb + lane * 2;

    for (int rl = wv * 25; rl < wv * 25 + 25; ++rl) {
        int beg = __builtin_amdgcn_readfirstlane(off2[rl]);
        int end = __builtin_amdgcn_readfirstlane(cur[rl]);
        if (beg >= end) continue;

        float ax[4] = {0.f, 0.f, 0.f, 0.f};
        float ay[4] = {0.f, 0.f, 0.f, 0.f};
        int e = beg;
        for (; e + 7 < end; e += 8) {
            int2 p[8];
            #pragma unroll
            for (int k = 0; k < 8; ++k) p[k] = sorted[e + k];
            #pragma unroll
            for (int k = 0; k < 8; ++k) {
                int col = p[k].x & 0x1FFFF;
                unsigned u = *(const unsigned*)(tb + (size_t)col * D);
                float v = __int_as_float(p[k].y);
                ax[k & 3] += v * __uint_as_float(u << 16);
                ay[k & 3] += v * __uint_as_float(u & 0xffff0000u);
            }
        }
        for (; e + 3 < end; e += 4) {
            int2 p[4];
            #pragma unroll
            for (int k = 0; k < 4; ++k) p[k] = sorted[e + k];
            #pragma unroll
            for (int k = 0; k < 4; ++k) {
                int col = p[k].x & 0x1FFFF;
                unsigned u = *(const unsigned*)(tb + (size_t)col * D);
                float v = __int_as_float(p[k].y);
                ax[k] += v * __uint_as_float(u << 16);
                ay[k] += v * __uint_as_float(u & 0xffff0000u);
            }
        }
        for (; e < end; ++e) {
            int2 p = sorted[e];
            int col = p.x & 0x1FFFF;
            unsigned u = *(const unsigned*)(tb + (size_t)col * D);
            float v = __int_as_float(p.y);
            ax[0] += v * __uint_as_float(u << 16);
            ay[0] += v * __uint_as_float(u & 0xffff0000u);
        }

        int row = b * BROWS + rl;
        f32x2* o = (f32x2*)(out + (size_t)row * D + lane * 2);
        f32x2 c = __builtin_nontemporal_load(o);
        c.x += (ax[0] + ax[1]) + (ax[2] + ax[3]);
        c.y += (ay[0] + ay[1]) + (ay[2] + ay[3]);
        __builtin_nontemporal_store(c, o);
    }
}

extern "C" void kernel_launch(void* const* d_in, const int* in_sizes, int n_in,
                              void* d_out, int out_size, void* d_ws, size_t ws_size,
                              hipStream_t stream) {
    const float* h     = (const float*)d_in[0];
    const float* eval_ = (const float*)d_in[1];
    const float* Wself = (const float*)d_in[2];
    const float* bself = (const float*)d_in[3];
    const float* Wnb   = (const float*)d_in[4];
    const float* bnb   = (const float*)d_in[5];
    const int*   erow  = (const int*)d_in[6];
    const int*   ecol  = (const int*)d_in[7];
    float* out = (float*)d_out;

    // ws: tmpb 25.6MB | epair 14.3MB | gcount 2KB
    char* p = (char*)d_ws;
    __bf16* tmpb    = (__bf16*)p;   p += (size_t)NT * GM * D * 2;
    int2*   epair   = (int2*)p;     p += (size_t)NBUCK * BCAP * 8;
    int*    gcount  = (int*)p;

    gemm_mfma<<<2 * GW, 256, 0, stream>>>(h, Wself, Wnb, bself, bnb, out, tmpb, gcount);
    wc_scatter<<<NCH, 512, 0, stream>>>(erow, ecol, eval_, gcount, epair);
    sort_aggregate<<<NBUCK, 512, 0, stream>>>(epair, gcount, tmpb, out);
}

// Round 13
// 238.827 us; speedup vs baseline: 1.0571x; 1.0571x over previous
//
#include <hip/hip_runtime.h>

// SAGEConv: out = h@W_self.T + b_self + b_nb + segsum(val * (h@W_nb.T)[col])
// R22 = R19 base (240.4us best) with gemm occupancy fixed the right way:
//     R21's paired-block scheme doubled h traffic (L2 pairing failed).
//     Here: 512-thread blocks (8 waves), each wave owns 32 dual-cols, so
//     ALL 256 dual-cols live in one block -> h staged ONCE per tile (1x
//     traffic) while per-wave regs drop to ~116 (wf 32 + acc 32 + pf 16).
//     __launch_bounds__(512,4) -> 4 waves/SIMD = 2x R10's residency.
//     Grid 512 x 512thr, ~3 tiles/block, same prefetch pipeline.
//     wc_scatter / sort_aggregate: exact R19 (proven).

constexpr int NN = 100000;
constexpr int NE = 1600000;
constexpr int D  = 128;
constexpr int NBUCK  = 500;                // buckets of BROWS rows
constexpr int BROWS  = 200;                // 500*200 = 100000 exactly
constexpr int BCAP   = 3584;               // mean 3200 + ~6.8 sigma
constexpr int CHUNK  = 4096;               // edges per wc chunk
constexpr int NCH    = (NE + CHUNK - 1) / CHUNK;   // 391
constexpr int GM     = 64;                 // gemm M-tile rows
constexpr int NT     = (NN + GM - 1) / GM; // 1563 tiles total
constexpr int GRID   = 512;                // persistent gemm blocks
constexpr int LP     = 132;                // LDS bf16 pitch (2-way = free)

typedef __bf16 bf16x8 __attribute__((ext_vector_type(8)));
typedef float  f32x4  __attribute__((ext_vector_type(4)));
typedef float  f32x2  __attribute__((ext_vector_type(2)));
typedef unsigned short u16x4 __attribute__((ext_vector_type(4)));

// ---------------- Dual GEMM (persistent, 8 slim waves / block) -----------
__global__ __launch_bounds__(512, 4) void gemm_mfma(
    const float* __restrict__ h,
    const float* __restrict__ Wself,
    const float* __restrict__ Wnb,
    const float* __restrict__ bself,
    const float* __restrict__ bnb,
    float* __restrict__ out,
    __bf16* __restrict__ tmpb,
    int* __restrict__ gcount)
{
    __shared__ __bf16 hs[2][GM * LP];   // 2 x 16.9 KB
    const int t    = threadIdx.x;
    const int w    = t >> 6;            // 8 waves
    const int lane = t & 63;
    const int l15  = lane & 15;
    const int quad = lane >> 4;

    // Zero gcount (500 ints): block 0 covers it.
    {
        int i = blockIdx.x * 512 + t;
        if (i < NBUCK) gcount[i] = 0;
    }

    // W frags (A operand): wave w owns dual-cols [w*32, w*32+32).
    // wrow = w*32 + ns*16 + l15, k = quad*8 + kk*32 + j.  wf[2][4] = 32 VGPR.
    bf16x8 wf[2][4];
    #pragma unroll
    for (int ns = 0; ns < 2; ++ns) {
        int wrow = w * 32 + ns * 16 + l15;
        const float* wr = (wrow < D) ? (Wself + (size_t)wrow * D)
                                     : (Wnb + (size_t)(wrow - D) * D);
        #pragma unroll
        for (int kk = 0; kk < 4; ++kk) {
            f32x4 lo = *(const f32x4*)(wr + kk * 32 + quad * 8);
            f32x4 hi = *(const f32x4*)(wr + kk * 32 + quad * 8 + 4);
            bf16x8 bb;
            #pragma unroll
            for (int j = 0; j < 4; ++j) { bb[j] = (__bf16)lo[j]; bb[4 + j] = (__bf16)hi[j]; }
            wf[ns][kk] = bb;
        }
    }
    // Bias vectors: only waves 0-3 (out cols) use them.
    f32x4 biasv[2];
    #pragma unroll
    for (int ns = 0; ns < 2; ++ns) {
        int col = w * 32 + ns * 16 + quad * 4;
        if (col < D) {
            f32x4 b1 = *(const f32x4*)(bself + col);
            f32x4 b2 = *(const f32x4*)(bnb + col);
            biasv[ns] = b1 + b2;
        } else biasv[ns] = (f32x4){0.f, 0.f, 0.f, 0.f};
    }

    // Per-thread staging geometry: 512 thr x 8 bf16 x 2 its = 8192 = 64x128.
    int srow[2], scol[2];
    #pragma unroll
    for (int it = 0; it < 2; ++it) {
        int idx = it * 4096 + t * 8;
        srow[it] = idx >> 7;
        scol[it] = idx & 127;
    }

    // Prologue: stage first tile into hs[0].
    {
        const int row0 = blockIdx.x * GM;
        #pragma unroll
        for (int it = 0; it < 2; ++it) {
            int gr = row0 + srow[it]; if (gr >= NN) gr = NN - 1;
            f32x4 lo = *(const f32x4*)(h + (size_t)gr * D + scol[it]);
            f32x4 hi = *(const f32x4*)(h + (size_t)gr * D + scol[it] + 4);
            bf16x8 v;
            #pragma unroll
            for (int j = 0; j < 4; ++j) { v[j] = (__bf16)lo[j]; v[4 + j] = (__bf16)hi[j]; }
            *(bf16x8*)(&hs[0][srow[it] * LP + scol[it]]) = v;
        }
    }
    __syncthreads();

    int buf = 0;
    for (int tile = blockIdx.x; tile < NT; tile += GRID) {
        const int row0 = tile * GM;
        const bool hasn = (tile + GRID) < NT;

        // Issue next tile's global loads NOW (in flight across MFMA).
        f32x4 pf[4];
        if (hasn) {
            const int nrow0 = (tile + GRID) * GM;
            #pragma unroll
            for (int it = 0; it < 2; ++it) {
                int gr = nrow0 + srow[it]; if (gr >= NN) gr = NN - 1;
                pf[it * 2]     = *(const f32x4*)(h + (size_t)gr * D + scol[it]);
                pf[it * 2 + 1] = *(const f32x4*)(h + (size_t)gr * D + scol[it] + 4);
            }
        }

        // Compute: acc[mi][ns] (32 accum regs). C-layout (swapped operands):
        //   C col(lane&15) = out-row = mi*16+l15 ; C row(quad*4+reg) = out-col.
        f32x4 acc[4][2];
        #pragma unroll
        for (int mi = 0; mi < 4; ++mi)
            #pragma unroll
            for (int ns = 0; ns < 2; ++ns) acc[mi][ns] = (f32x4){0.f, 0.f, 0.f, 0.f};

        const __bf16* hb = hs[buf];
        #pragma unroll
        for (int mi = 0; mi < 4; ++mi) {
            bf16x8 hf[4];
            #pragma unroll
            for (int kk = 0; kk < 4; ++kk)
                hf[kk] = *(const bf16x8*)(&hb[(mi * 16 + l15) * LP + quad * 8 + kk * 32]);
            #pragma unroll
            for (int ns = 0; ns < 2; ++ns)
                #pragma unroll
                for (int kk = 0; kk < 4; ++kk)
                    acc[mi][ns] = __builtin_amdgcn_mfma_f32_16x16x32_bf16(wf[ns][kk], hf[kk], acc[mi][ns], 0, 0, 0);
        }

        // Convert + write the prefetched tile into the other LDS buffer.
        if (hasn) {
            #pragma unroll
            for (int it = 0; it < 2; ++it) {
                bf16x8 v;
                #pragma unroll
                for (int j = 0; j < 4; ++j) {
                    v[j]     = (__bf16)pf[it * 2][j];
                    v[4 + j] = (__bf16)pf[it * 2 + 1][j];
                }
                *(bf16x8*)(&hs[buf ^ 1][srow[it] * LP + scol[it]]) = v;
            }
        }
        __syncthreads();

        // Epilogue: waves 0-3 -> out (f32 + bias); waves 4-7 -> tmpb (bf16).
        #pragma unroll
        for (int mi = 0; mi < 4; ++mi) {
            int row = row0 + mi * 16 + l15;
            if (row < NN) {
                if (w < 4) {
                    #pragma unroll
                    for (int ns = 0; ns < 2; ++ns) {
                        int col = w * 32 + ns * 16 + quad * 4;
                        *(f32x4*)(out + (size_t)row * D + col) = acc[mi][ns] + biasv[ns];
                    }
                } else {
                    #pragma unroll
                    for (int ns = 0; ns < 2; ++ns) {
                        int col = (w - 4) * 32 + ns * 16 + quad * 4;
                        u16x4 v;
                        #pragma unroll
                        for (int i = 0; i < 4; ++i) {
                            __bf16 b = (__bf16)acc[mi][ns][i];
                            v[i] = *(unsigned short*)&b;
                        }
                        *(u16x4*)(tmpb + (size_t)row * D + col) = v;
                    }
                }
            }
        }
        buf ^= 1;
    }
}

// ------- Write-combined bucket scatter (500 bins, CHUNK 4096, 512 thr) ---
__global__ __launch_bounds__(512) void wc_scatter(
    const int* __restrict__ erow, const int* __restrict__ ecol,
    const float* __restrict__ eval_,
    int* __restrict__ gcount, int2* __restrict__ epair)
{
    __shared__ int  cnt[NBUCK];
    __shared__ int  lscan[NBUCK];
    __shared__ int  gbase[NBUCK];
    __shared__ int  ss[512];
    __shared__ int2 sbuf[CHUNK];
    __shared__ int  saddr[CHUNK];
    __shared__ int  s_total;

    const int t  = threadIdx.x;
    const int c0 = blockIdx.x * CHUNK;

    for (int b = t; b < NBUCK; b += 512) cnt[b] = 0;
    __syncthreads();

    int   bp[8];       // b | rlo<<9 | pos<<17  (or -1 if OOB)
    int   colr[8];
    float valr[8];
    #pragma unroll
    for (int j = 0; j < 8; ++j) {
        int e = c0 + j * 512 + t;
        if (e < NE) {
            int r   = erow[e];
            colr[j] = ecol[e];
            valr[j] = eval_[e];
            int b   = r / BROWS;
            int rlo = r - b * BROWS;
            int pos = atomicAdd(&cnt[b], 1);
            bp[j]   = b | (rlo << 9) | (pos << 17);
        } else bp[j] = -1;
    }
    __syncthreads();

    // Scan 512 slots, 1/thread Hillis-Steele.
    ss[t] = (t < NBUCK) ? cnt[t] : 0;
    __syncthreads();
    for (int off = 1; off < 512; off <<= 1) {
        int v = ss[t] + ((t >= off) ? ss[t - off] : 0);
        __syncthreads();
        ss[t] = v;
        __syncthreads();
    }
    if (t < NBUCK) {
        int n = cnt[t];
        lscan[t] = ss[t] - n;
        gbase[t] = (n > 0) ? atomicAdd(&gcount[t], n) : 0;
    }
    if (t == 0) s_total = ss[511];
    __syncthreads();

    #pragma unroll
    for (int j = 0; j < 8; ++j) {
        if (bp[j] >= 0) {
            int b   = bp[j] & 511;
            int rlo = (bp[j] >> 9) & 255;
            int pos = bp[j] >> 17;
            int slot = lscan[b] + pos;
            sbuf[slot]  = make_int2(colr[j] | (rlo << 17), __float_as_int(valr[j]));
            saddr[slot] = b * BCAP + gbase[b] + pos;
        }
    }
    __syncthreads();

    int ce = s_total;
    for (int i = t; i < ce; i += 512)
        epair[saddr[i]] = sbuf[i];
}

// ---------------- Fused bucket sort + aggregate (exact R19) --------------
__global__ __launch_bounds__(512, 4) void sort_aggregate(
    const int2* __restrict__ epair, const int* __restrict__ gcount,
    const __bf16* __restrict__ tmpb, float* __restrict__ out)
{
    __shared__ int  cnt[BROWS];
    __shared__ int  off2[BROWS];
    __shared__ int  cur[BROWS];
    __shared__ int  ss[256];
    __shared__ int2 sorted[BCAP];

    const int t = threadIdx.x;
    const int b = blockIdx.x;
    int n = gcount[b];
    if (n > BCAP) n = BCAP;
    const int2* src = epair + (size_t)b * BCAP;

    if (t < BROWS) cnt[t] = 0;
    __syncthreads();

    int2 r[8];
    int  nr = 0;
    for (int i = t; i < n; i += 512) {
        int2 p = src[i];
        r[nr++] = p;
        atomicAdd(&cnt[(p.x >> 17) & 255], 1);
    }
    __syncthreads();

    if (t < 256) ss[t] = (t < BROWS) ? cnt[t] : 0;
    __syncthreads();
    for (int o = 1; o < 256; o <<= 1) {
        int y = 0;
        if (t < 256 && t >= o) y = ss[t - o];
        __syncthreads();
        if (t < 256) ss[t] += y;
        __syncthreads();
    }
    if (t < BROWS) {
        int v = cnt[t];
        off2[t] = ss[t] - v;
        cur[t]  = ss[t] - v;
    }
    __syncthreads();

    for (int j = 0; j < nr; ++j) {
        int slot = atomicAdd(&cur[(r[j].x >> 17) & 255], 1);
        sorted[slot] = r[j];
    }
    __syncthreads();
    // Now: row rl's edges are sorted[off2[rl] .. cur[rl]).

    // ---- Aggregate phase: 8 waves x 25 rows, gather tmpb, RMW out. ----
    const int wv   = t >> 6;
    const int lane = t & 63;
    const __bf16* tb = tmpb + lane * 2;

    for (int rl = wv * 25; rl < wv * 25 + 25; ++rl) {
        int beg = __builtin_amdgcn_readfirstlane(off2[rl]);
        int end = __builtin_amdgcn_readfirstlane(cur[rl]);
        if (beg >= end) continue;

        float ax[4] = {0.f, 0.f, 0.f, 0.f};
        float ay[4] = {0.f, 0.f, 0.f, 0.f};
        int e = beg;
        for (; e + 7 < end; e += 8) {
            int2 p[8];
            #pragma unroll
            for (int k = 0; k < 8; ++k) p[k] = sorted[e + k];
            #pragma unroll
            for (int k = 0; k < 8; ++k) {
                int col = p[k].x & 0x1FFFF;
                unsigned u = *(const unsigned*)(tb + (size_t)col * D);
                float v = __int_as_float(p[k].y);
                ax[k & 3] += v * __uint_as_float(u << 16);
                ay[k & 3] += v * __uint_as_float(u & 0xffff0000u);
            }
        }
        for (; e + 3 < end; e += 4) {
            int2 p[4];
            #pragma unroll
            for (int k = 0; k < 4; ++k) p[k] = sorted[e + k];
            #pragma unroll
            for (int k = 0; k < 4; ++k) {
                int col = p[k].x & 0x1FFFF;
                unsigned u = *(const unsigned*)(tb + (size_t)col * D);
                float v = __int_as_float(p[k].y);
                ax[k] += v * __uint_as_float(u << 16);
                ay[k] += v * __uint_as_float(u & 0xffff0000u);
            }
        }
        for (; e < end; ++e) {
            int2 p = sorted[e];
            int col = p.x & 0x1FFFF;
            unsigned u = *(const unsigned*)(tb + (size_t)col * D);
            float v = __int_as_float(p.y);
            ax[0] += v * __uint_as_float(u << 16);
            ay[0] += v * __uint_as_float(u & 0xffff0000u);
        }

        int row = b * BROWS + rl;
        f32x2* o = (f32x2*)(out + (size_t)row * D + lane * 2);
        f32x2 c = __builtin_nontemporal_load(o);
        c.x += (ax[0] + ax[1]) + (ax[2] + ax[3]);
        c.y += (ay[0] + ay[1]) + (ay[2] + ay[3]);
        __builtin_nontemporal_store(c, o);
    }
}

extern "C" void kernel_launch(void* const* d_in, const int* in_sizes, int n_in,
                              void* d_out, int out_size, void* d_ws, size_t ws_size,
                              hipStream_t stream) {
    const float* h     = (const float*)d_in[0];
    const float* eval_ = (const float*)d_in[1];
    const float* Wself = (const float*)d_in[2];
    const float* bself = (const float*)d_in[3];
    const float* Wnb   = (const float*)d_in[4];
    const float* bnb   = (const float*)d_in[5];
    const int*   erow  = (const int*)d_in[6];
    const int*   ecol  = (const int*)d_in[7];
    float* out = (float*)d_out;

    // ws: tmpb 25.6MB | epair 14.3MB | gcount 2KB
    char* p = (char*)d_ws;
    __bf16* tmpb    = (__bf16*)p;   p += (size_t)NT * GM * D * 2;
    int2*   epair   = (int2*)p;     p += (size_t)NBUCK * BCAP * 8;
    int*    gcount  = (int*)p;

    gemm_mfma<<<GRID, 512, 0, stream>>>(h, Wself, Wnb, bself, bnb, out, tmpb, gcount);
    wc_scatter<<<NCH, 512, 0, stream>>>(erow, ecol, eval_, gcount, epair);
    sort_aggregate<<<NBUCK, 512, 0, stream>>>(epair, gcount, tmpb, out);
}